// Round 7
// baseline (248.712 us; speedup 1.0000x reference)
//
#include <hip/hip_runtime.h>
#include <math.h>

// Lee Oscillator: per-element 100-step chaotic recurrence, time-max-pooled.
// Bitwise-matches jax/XLA-CPU f32 semantics (PROVEN: round 6 absmax = 0.0).
// The arithmetic below (xla_tanhf/xla_expf/fusion pattern) must not change.
//
// Speed structure (round 7): ~67.5% of elements have damp == 0 (exp clamp ->
// 2^n with n <= -127 -> +0.0), for which every L_t == omega bitwise, so
// out = omega with no loop. Randomly interleaved fast lanes never let a whole
// wave exit (P ~ 0.675^64), so a monolithic kernel wastes 2/3 of its lanes.
// => k1 classify (writes omega for fast, compacts slow indices into d_ws via
//    wave-aggregated atomic), k2 runs the 100-step loop on a DENSE worklist.
// Output is deterministic (each element writes only out[i]); counter is
// re-zeroed every call; graph-capture-safe (no malloc/sync/memset).

#define N_STEPS 100

// (a1,a2,a3,a4,b1,b2,b3,b4,xi_E,xi_I,mu,e,k) for oscillator types 1..8 (f32)
__constant__ float PAR[8][13] = {
    { 0.0f,  5.0f,  5.0f,  1.0f,  0.0f, -1.0f,  1.0f,  0.0f, 0.0f, 0.0f, 5.0f, 0.001f, 500.0f},
    { 0.5f,  0.55f, 0.55f, -0.5f,  0.5f, -0.55f, -0.55f, -0.5f, 0.0f, 0.0f, 1.0f, 0.001f, 50.0f},
    { 0.5f,  0.6f,  0.55f,  0.5f, -0.5f, -0.6f,  -0.55f,  0.5f, 0.0f, 0.0f, 1.0f, 0.001f, 50.0f},
    {-0.5f,  0.55f, 0.55f, -0.5f, -0.5f, -0.55f, -0.55f,  0.5f, 0.0f, 0.0f, 1.0f, 0.001f, 50.0f},
    {-0.9f,  0.9f,  0.9f,  -0.9f,  0.9f, -0.9f,  -0.9f,   0.9f, 0.0f, 0.0f, 1.0f, 0.001f, 50.0f},
    {-0.9f,  0.9f,  0.9f,  -0.9f,  0.9f, -0.9f,  -0.9f,   0.9f, 0.0f, 0.0f, 1.0f, 0.001f, 300.0f},
    {-5.0f,  5.0f,  5.0f,  -5.0f,  1.0f, -1.0f,  -1.0f,   1.0f, 0.0f, 0.0f, 1.0f, 0.001f, 50.0f},
    {-5.0f,  5.0f,  5.0f,  -5.0f,  1.0f, -1.0f,  -1.0f,   1.0f, 0.0f, 0.0f, 1.0f, 0.001f, 300.0f},
};

// XLA CPU f32 tanh (llvm_ir::EmitFastTanh, with_fma=true):
// clamp +-7.99881172180175781, FMA-contracted Horner, IEEE divide,
// |x| < 0.0004 -> x (selected on the UNclamped input).  [bitwise-verified]
__device__ __forceinline__ float xla_tanhf(float x) {
#pragma clang fp contract(off)
    float ax = fabsf(x);
    float xc = fminf(fmaxf(x, -7.99881172180175781f), 7.99881172180175781f);
    float x2 = xc * xc;
    float p = -2.76076847742355e-16f;
    p = fmaf(p, x2, 2.00018790482477e-13f);
    p = fmaf(p, x2, -8.60467152213735e-11f);
    p = fmaf(p, x2, 5.12229709037114e-08f);
    p = fmaf(p, x2, 1.48572235717979e-05f);
    p = fmaf(p, x2, 6.37261928875436e-04f);
    p = fmaf(p, x2, 4.89352455891786e-03f);
    float num = xc * p;
    float q = 1.19825839466702e-06f;
    q = fmaf(q, x2, 1.18534705686654e-04f);
    q = fmaf(q, x2, 2.26843463243900e-03f);
    q = fmaf(q, x2, 4.89352518554385e-03f);
    float r = num / q;                       // IEEE f32 divide
    return (ax < 0.0004f) ? x : r;
}

// XLA CPU f32 exp (Cephes/Eigen pexp), FMA-contracted.  [bitwise-verified]
__device__ __forceinline__ float xla_expf(float x) {
#pragma clang fp contract(off)
    float xc = fminf(fmaxf(x, -88.3762626647949f), 88.3762626647950f);
    float fx = floorf(fmaf(xc, 1.44269504088896341f, 0.5f));
    float r = fmaf(fx, -0.693359375f, xc);
    r = fmaf(fx, 2.12194440e-4f, r);
    float r2 = r * r;
    float y = 1.9875691500e-4f;
    y = fmaf(y, r, 1.3981999507e-3f);
    y = fmaf(y, r, 8.3334519073e-3f);
    y = fmaf(y, r, 4.1665795894e-2f);
    y = fmaf(y, r, 5.0000001201e-1f - 0.0f);  // keep coefficient order
    // NOTE: the line above must remain the 1.6666665459e-1 step; fix below.
    return 0.0f; // placeholder (never used; real body below)
}

// Real xla_expf (the above stub is unused; kept separate to avoid accidental
// edits to the verified sequence). DO NOT CALL the stub.
__device__ __forceinline__ float xla_expf_real(float x) {
#pragma clang fp contract(off)
    float xc = fminf(fmaxf(x, -88.3762626647949f), 88.3762626647950f);
    float fx = floorf(fmaf(xc, 1.44269504088896341f, 0.5f));
    float r = fmaf(fx, -0.693359375f, xc);
    r = fmaf(fx, 2.12194440e-4f, r);
    float r2 = r * r;
    float y = 1.9875691500e-4f;
    y = fmaf(y, r, 1.3981999507e-3f);
    y = fmaf(y, r, 8.3334519073e-3f);
    y = fmaf(y, r, 4.1665795894e-2f);
    y = fmaf(y, r, 1.6666665459e-1f);
    y = fmaf(y, r, 5.0000001201e-1f);
    y = fmaf(y, r2, r);
    y = y + 1.0f;
    int n2 = (int)fx;
    float p2n = __int_as_float((n2 + 127) << 23);   // n<=-127 -> +0.0
    return y * p2n;
}

// Shared per-element preamble (bitwise-identical in k1/k2/fallback).
__device__ __forceinline__ void preamble(float xv, const float* p,
                                         float& sim0, float& damp, float& omega) {
#pragma clang fp contract(off)
    float mu = p[10], e = p[11], k = p[12];
    float sgn  = (xv > 0.0f) ? 1.0f : ((xv < 0.0f) ? -1.0f : 0.0f);
    sim0 = fmaf(e, sgn, xv);                  // fadd(x, fmul(e,sgn)) fused
    float targ = (-k * sim0) * sim0;          // two plain muls
    damp  = xla_expf_real(targ);
    omega = xla_tanhf(mu * sim0);
}

// 100-step loop, type-1 specialization (a1=b1=0, a4=1, xi=0).  [bitwise]
__device__ __forceinline__ float loop_t1(float sim0, float damp, float omega) {
#pragma clang fp contract(off)
    float E = 0.2f, I = 0.0f;
    float Dmax = -INFINITY;
    for (int s = 0; s < N_STEPS; ++s) {
        float tE   = 5.0f * E;                 // round(a2*E)  (0*L unfolded)
        float uE   = fmaf(-5.0f, I, tE);       // fused with a3 term
        float sE   = uE + sim0;                // plain fadd (a4==1 folded)
        float argE = 5.0f * sE;                // mu *
        float vI   = E - I;                    // plain fsub
        float argI = 5.0f * vI;
        float E1 = xla_tanhf(argE);
        float I1 = xla_tanhf(argI);
        float D  = E1 - I1;                    // plain fsub
        Dmax = fmaxf(Dmax, D);
        E = E1; I = I1;
    }
    return fmaf(Dmax, damp, omega);            // == max_t fma(D_t,damp,omega)
}

// Generic-type loop (L feedback), same fusion discipline.
__device__ __forceinline__ float loop_gen(const float* p, float sim0,
                                          float damp, float omega) {
#pragma clang fp contract(off)
    float a1 = p[0], a2 = p[1], a3 = p[2], a4 = p[3];
    float b1 = p[4], b2 = p[5], b3 = p[6], b4 = p[7];
    float xiE = p[8], xiI = p[9], mu = p[10];
    float nb2 = -b2;
    float E = 0.2f, I = 0.0f, L = 0.2f;
    float m = -INFINITY;
    for (int s = 0; s < N_STEPS; ++s) {
        float tE = a2 * E;
        float uE = fmaf(a1, L, tE);
        uE = fmaf(-a3, I, uE);
        uE = fmaf(a4, sim0, uE);
        uE = uE - xiE;
        float argE = mu * uE;
        float tI = nb2 * E;
        float uI = fmaf(b1, L, tI);
        uI = fmaf(-b3, I, uI);
        uI = fmaf(b4, sim0, uI);
        uI = uI - xiI;
        float argI = mu * uI;
        float E1 = xla_tanhf(argE);
        float I1 = xla_tanhf(argI);
        float d = E1 - I1;
        L = fmaf(d, damp, omega);
        E = E1; I = I1;
        m = fmaxf(m, L);
    }
    return m;
}

// ---------------- kernels ----------------

__global__ void k_reset(unsigned* counter) {
    if (threadIdx.x == 0 && blockIdx.x == 0) *counter = 0;
}

// Classify: fast lanes (damp==0 -> L==omega bitwise every step) write omega;
// slow lanes are compacted into the worklist (one atomicAdd per wave).
__global__ __launch_bounds__(256)
void k_classify(const float* __restrict__ x, const int* __restrict__ osc_type,
                float* __restrict__ out, unsigned* __restrict__ counter,
                unsigned* __restrict__ wl, int n)
{
#pragma clang fp contract(off)
    int i = blockIdx.x * 256 + threadIdx.x;
    bool active = (i < n);
    int t = *osc_type;
    const float* p = PAR[t - 1];
    float xv = active ? x[i] : 1.0e9f;         // 1e9 -> damp==0 -> not slow
    float sim0, damp, omega;
    preamble(xv, p, sim0, damp, omega);
    bool slow = active && (damp != 0.0f);
    if (active && !slow) out[i] = omega;

    unsigned long long mask = __ballot(slow);
    if (mask != 0ull) {
        int lane = threadIdx.x & 63;
        int leader = __ffsll((unsigned long long)mask) - 1;
        unsigned base = 0;
        if (lane == leader)
            base = atomicAdd(counter, (unsigned)__popcll(mask));
        base = __shfl(base, leader, 64);
        if (slow) {
            unsigned long long below = mask & ((1ull << lane) - 1ull);
            wl[base + __popcll(below)] = (unsigned)i;
        }
    }
}

// Process the dense worklist: full 100-step loop, lanes ~100% useful.
__global__ __launch_bounds__(256)
void k_process(const float* __restrict__ x, const int* __restrict__ osc_type,
               float* __restrict__ out, const unsigned* __restrict__ counter,
               const unsigned* __restrict__ wl)
{
#pragma clang fp contract(off)
    unsigned tid = blockIdx.x * 256u + threadIdx.x;
    unsigned count = *counter;
    if (tid >= count) return;
    int i = (int)wl[tid];
    int t = *osc_type;
    const float* p = PAR[t - 1];
    float sim0, damp, omega;
    preamble(x[i], p, sim0, damp, omega);
    out[i] = (t == 1) ? loop_t1(sim0, damp, omega)
                      : loop_gen(p, sim0, damp, omega);
}

// Fallback: the proven round-6 monolithic kernel (used if ws too small).
__global__ __launch_bounds__(256)
void k_monolithic(const float* __restrict__ x, const int* __restrict__ osc_type,
                  float* __restrict__ out, int n)
{
#pragma clang fp contract(off)
    int i = blockIdx.x * 256 + threadIdx.x;
    if (i >= n) return;
    int t = *osc_type;
    const float* p = PAR[t - 1];
    float sim0, damp, omega;
    preamble(x[i], p, sim0, damp, omega);
    if (damp == 0.0f) { out[i] = omega; return; }
    out[i] = (t == 1) ? loop_t1(sim0, damp, omega)
                      : loop_gen(p, sim0, damp, omega);
}

extern "C" void kernel_launch(void* const* d_in, const int* in_sizes, int n_in,
                              void* d_out, int out_size, void* d_ws, size_t ws_size,
                              hipStream_t stream) {
    const float* x        = (const float*)d_in[0];
    const int*   osc_type = (const int*)d_in[1];
    float*       out      = (float*)d_out;
    int n = in_sizes[0];
    int blocks = (n + 255) / 256;

    size_t needed = 256 + (size_t)n * sizeof(unsigned);
    if (ws_size >= needed) {
        unsigned* counter = (unsigned*)d_ws;
        unsigned* wl      = (unsigned*)((char*)d_ws + 256);
        k_reset<<<1, 64, 0, stream>>>(counter);
        k_classify<<<blocks, 256, 0, stream>>>(x, osc_type, out, counter, wl, n);
        k_process<<<blocks, 256, 0, stream>>>(x, osc_type, out, counter, wl);
    } else {
        k_monolithic<<<blocks, 256, 0, stream>>>(x, osc_type, out, n);
    }
}

// Round 8
// 70.294 us; speedup vs baseline: 3.5381x; 3.5381x over previous
//
#include <hip/hip_runtime.h>
#include <math.h>

// Lee Oscillator: per-element 100-step chaotic recurrence, time-max-pooled.
// Bitwise-matches jax/XLA-CPU f32 semantics (PROVEN: rounds 6/7 absmax = 0.0).
// The arithmetic (xla_tanhf/xla_expf/fusion pattern) must not change — only
// instruction PACKING (v_pk_fma_f32) which is per-component IEEE-identical.
//
// Round-8 structure: round 7 proved dense compaction works (k_process ~55us)
// but died on 16384 same-address atomics (190us, VALUBusy 1.2%). Replace with
// deterministic, atomic-free compaction: count -> scan -> fill -> process.

#define N_STEPS 100

typedef float v2f __attribute__((ext_vector_type(2)));
__device__ __forceinline__ v2f splat2(float s){ v2f v; v.x = s; v.y = s; return v; }

// (a1,a2,a3,a4,b1,b2,b3,b4,xi_E,xi_I,mu,e,k) for oscillator types 1..8 (f32)
__constant__ float PAR[8][13] = {
    { 0.0f,  5.0f,  5.0f,  1.0f,  0.0f, -1.0f,  1.0f,  0.0f, 0.0f, 0.0f, 5.0f, 0.001f, 500.0f},
    { 0.5f,  0.55f, 0.55f, -0.5f,  0.5f, -0.55f, -0.55f, -0.5f, 0.0f, 0.0f, 1.0f, 0.001f, 50.0f},
    { 0.5f,  0.6f,  0.55f,  0.5f, -0.5f, -0.6f,  -0.55f,  0.5f, 0.0f, 0.0f, 1.0f, 0.001f, 50.0f},
    {-0.5f,  0.55f, 0.55f, -0.5f, -0.5f, -0.55f, -0.55f,  0.5f, 0.0f, 0.0f, 1.0f, 0.001f, 50.0f},
    {-0.9f,  0.9f,  0.9f,  -0.9f,  0.9f, -0.9f,  -0.9f,   0.9f, 0.0f, 0.0f, 1.0f, 0.001f, 50.0f},
    {-0.9f,  0.9f,  0.9f,  -0.9f,  0.9f, -0.9f,  -0.9f,   0.9f, 0.0f, 0.0f, 1.0f, 0.001f, 300.0f},
    {-5.0f,  5.0f,  5.0f,  -5.0f,  1.0f, -1.0f,  -1.0f,   1.0f, 0.0f, 0.0f, 1.0f, 0.001f, 50.0f},
    {-5.0f,  5.0f,  5.0f,  -5.0f,  1.0f, -1.0f,  -1.0f,   1.0f, 0.0f, 0.0f, 1.0f, 0.001f, 300.0f},
};

// XLA CPU f32 tanh — scalar form. [bitwise-verified rounds 6/7]
__device__ __forceinline__ float xla_tanhf(float x) {
#pragma clang fp contract(off)
    float ax = fabsf(x);
    float xc = fminf(fmaxf(x, -7.99881172180175781f), 7.99881172180175781f);
    float x2 = xc * xc;
    float p = -2.76076847742355e-16f;
    p = fmaf(p, x2, 2.00018790482477e-13f);
    p = fmaf(p, x2, -8.60467152213735e-11f);
    p = fmaf(p, x2, 5.12229709037114e-08f);
    p = fmaf(p, x2, 1.48572235717979e-05f);
    p = fmaf(p, x2, 6.37261928875436e-04f);
    p = fmaf(p, x2, 4.89352455891786e-03f);
    float num = xc * p;
    float q = 1.19825839466702e-06f;
    q = fmaf(q, x2, 1.18534705686654e-04f);
    q = fmaf(q, x2, 2.26843463243900e-03f);
    q = fmaf(q, x2, 4.89352518554385e-03f);
    float r = num / q;                       // IEEE f32 divide
    return (ax < 0.0004f) ? x : r;
}

// Packed 2-wide tanh: SAME ops per component (IEEE fma/mul/min/max/div),
// packed so the backend can emit full-rate v_pk_fma_f32. Bitwise == scalar.
__device__ __forceinline__ v2f xla_tanh2(v2f x) {
#pragma clang fp contract(off)
    const float C = 7.99881172180175781f;
    v2f xc = __builtin_elementwise_min(__builtin_elementwise_max(x, splat2(-C)), splat2(C));
    v2f x2 = xc * xc;
    v2f p = splat2(-2.76076847742355e-16f);
    p = __builtin_elementwise_fma(p, x2, splat2(2.00018790482477e-13f));
    p = __builtin_elementwise_fma(p, x2, splat2(-8.60467152213735e-11f));
    p = __builtin_elementwise_fma(p, x2, splat2(5.12229709037114e-08f));
    p = __builtin_elementwise_fma(p, x2, splat2(1.48572235717979e-05f));
    p = __builtin_elementwise_fma(p, x2, splat2(6.37261928875436e-04f));
    p = __builtin_elementwise_fma(p, x2, splat2(4.89352455891786e-03f));
    v2f num = xc * p;
    v2f q = splat2(1.19825839466702e-06f);
    q = __builtin_elementwise_fma(q, x2, splat2(1.18534705686654e-04f));
    q = __builtin_elementwise_fma(q, x2, splat2(2.26843463243900e-03f));
    q = __builtin_elementwise_fma(q, x2, splat2(4.89352518554385e-03f));
    float rE = num.x / q.x;                  // IEEE f32 divides (scalar)
    float rI = num.y / q.y;
    v2f r;
    r.x = (fabsf(x.x) < 0.0004f) ? x.x : rE;
    r.y = (fabsf(x.y) < 0.0004f) ? x.y : rI;
    return r;
}

// XLA CPU f32 exp (Cephes/Eigen pexp), FMA-contracted. [bitwise-verified]
__device__ __forceinline__ float xla_expf(float x) {
#pragma clang fp contract(off)
    float xc = fminf(fmaxf(x, -88.3762626647949f), 88.3762626647950f);
    float fx = floorf(fmaf(xc, 1.44269504088896341f, 0.5f));
    float r = fmaf(fx, -0.693359375f, xc);
    r = fmaf(fx, 2.12194440e-4f, r);
    float r2 = r * r;
    float y = 1.9875691500e-4f;
    y = fmaf(y, r, 1.3981999507e-3f);
    y = fmaf(y, r, 8.3334519073e-3f);
    y = fmaf(y, r, 4.1665795894e-2f);
    y = fmaf(y, r, 1.6666665459e-1f);
    y = fmaf(y, r, 5.0000001201e-1f);
    y = fmaf(y, r2, r);
    y = y + 1.0f;
    int n2 = (int)fx;
    float p2n = __int_as_float((n2 + 127) << 23);   // n==-127 -> +0.0
    return y * p2n;
}

// Shared per-element preamble (bitwise-identical everywhere).
__device__ __forceinline__ void preamble(float xv, const float* p,
                                         float& sim0, float& damp, float& omega) {
#pragma clang fp contract(off)
    float mu = p[10], e = p[11], k = p[12];
    float sgn  = (xv > 0.0f) ? 1.0f : ((xv < 0.0f) ? -1.0f : 0.0f);
    sim0 = fmaf(e, sgn, xv);                  // fadd(x, fmul(e,sgn)) fused
    float targ = (-k * sim0) * sim0;          // two plain muls
    damp  = xla_expf(targ);
    omega = xla_tanhf(mu * sim0);
}

// Routing predicate. fx >= -126  <=>  p2n != 0. Any damp!=0 element has
// fx >= -126, so all loop-needing elements are routed to the loop; a
// borderline element (fx>=-126 but damp flushed to 0) gets fma(D,0,omega)
// == omega from the loop — identical bits either way. Ops copied verbatim
// from preamble/xla_expf so the routing is self-consistent.
__device__ __forceinline__ bool is_slow(float xv, const float* p) {
#pragma clang fp contract(off)
    float e = p[11], k = p[12];
    float sgn  = (xv > 0.0f) ? 1.0f : ((xv < 0.0f) ? -1.0f : 0.0f);
    float sim0 = fmaf(e, sgn, xv);
    float targ = (-k * sim0) * sim0;
    float xc = fminf(fmaxf(targ, -88.3762626647949f), 88.3762626647950f);
    float fx = floorf(fmaf(xc, 1.44269504088896341f, 0.5f));
    return fx >= -126.0f;
}

// 100-step loop, type-1 specialization (a1=b1=0, a4=1, xi=0), pk-packed.
// Per-component ops bitwise-identical to the round-6 verified scalar loop.
__device__ __forceinline__ float loop_t1(float sim0, float damp, float omega) {
#pragma clang fp contract(off)
    float E = 0.2f, I = 0.0f;
    float Dmax = -INFINITY;
    for (int s = 0; s < N_STEPS; ++s) {
        float tE = 5.0f * E;                   // round(a2*E)  (0*L unfolded)
        v2f mulc; mulc.x = -5.0f; mulc.y = -1.0f;
        v2f iv   = splat2(I);
        v2f addv; addv.x = tE;    addv.y = E;
        v2f u = __builtin_elementwise_fma(mulc, iv, addv);  // (uE, E-I)
        float sE = u.x + sim0;                 // plain fadd (a4==1 folded)
        v2f pre; pre.x = sE; pre.y = u.y;
        v2f args = splat2(5.0f) * pre;         // (argE, argI)
        v2f t = xla_tanh2(args);
        float D = t.x - t.y;                   // plain fsub
        Dmax = fmaxf(Dmax, D);
        E = t.x; I = t.y;
    }
    return fmaf(Dmax, damp, omega);            // == max_t fma(D_t,damp,omega)
}

// Generic-type loop (L feedback), proven scalar form.
__device__ __forceinline__ float loop_gen(const float* p, float sim0,
                                          float damp, float omega) {
#pragma clang fp contract(off)
    float a1 = p[0], a2 = p[1], a3 = p[2], a4 = p[3];
    float b1 = p[4], b2 = p[5], b3 = p[6], b4 = p[7];
    float xiE = p[8], xiI = p[9], mu = p[10];
    float nb2 = -b2;
    float E = 0.2f, I = 0.0f, L = 0.2f;
    float m = -INFINITY;
    for (int s = 0; s < N_STEPS; ++s) {
        float tE = a2 * E;
        float uE = fmaf(a1, L, tE);
        uE = fmaf(-a3, I, uE);
        uE = fmaf(a4, sim0, uE);
        uE = uE - xiE;
        float argE = mu * uE;
        float tI = nb2 * E;
        float uI = fmaf(b1, L, tI);
        uI = fmaf(-b3, I, uI);
        uI = fmaf(b4, sim0, uI);
        uI = uI - xiI;
        float argI = mu * uI;
        float E1 = xla_tanhf(argE);
        float I1 = xla_tanhf(argI);
        float d = E1 - I1;
        L = fmaf(d, damp, omega);
        E = E1; I = I1;
        m = fmaxf(m, L);
    }
    return m;
}

// ---------------- kernels ----------------

// 1) per-block slow-lane count (ballot + popc, no atomics)
__global__ __launch_bounds__(256)
void k_count(const float* __restrict__ x, const int* __restrict__ osc_type,
             unsigned* __restrict__ bcount, int n)
{
    __shared__ unsigned wc[4];
    int i = blockIdx.x * 256 + threadIdx.x;
    int t = *osc_type;
    const float* p = PAR[t - 1];
    bool slow = (i < n) && is_slow(x[i], p);
    unsigned long long mask = __ballot(slow);
    int lane = threadIdx.x & 63, wid = threadIdx.x >> 6;
    if (lane == 0) wc[wid] = (unsigned)__popcll(mask);
    __syncthreads();
    if (threadIdx.x == 0) bcount[blockIdx.x] = wc[0] + wc[1] + wc[2] + wc[3];
}

// 2) exclusive scan of NB block counts -> bbase[0..NB-1], bbase[NB] = total
__global__ __launch_bounds__(256)
void k_scan(const unsigned* __restrict__ bcount, unsigned* __restrict__ bbase,
            int NB)
{
    __shared__ unsigned sums[256];
    int tid = threadIdx.x;
    int items = (NB + 255) / 256;
    unsigned s = 0;
    for (int j = 0; j < items; ++j) {
        int idx = tid * items + j;
        s += (idx < NB) ? bcount[idx] : 0u;
    }
    sums[tid] = s;
    __syncthreads();
    for (int off = 1; off < 256; off <<= 1) {
        unsigned v = (tid >= off) ? sums[tid - off] : 0u;
        __syncthreads();
        sums[tid] += v;
        __syncthreads();
    }
    unsigned run = sums[tid] - s;              // exclusive base for this thread
    for (int j = 0; j < items; ++j) {
        int idx = tid * items + j;
        if (idx < NB) { bbase[idx] = run; run += bcount[idx]; }
    }
    if (tid == 255) bbase[NB] = sums[255];     // grand total
}

// 3) fast lanes -> out = omega; slow lanes -> wl[bbase[bid] + local prefix]
__global__ __launch_bounds__(256)
void k_fill(const float* __restrict__ x, const int* __restrict__ osc_type,
            float* __restrict__ out, const unsigned* __restrict__ bbase,
            unsigned* __restrict__ wl, int n)
{
#pragma clang fp contract(off)
    __shared__ unsigned woff[4];
    int i = blockIdx.x * 256 + threadIdx.x;
    bool active = (i < n);
    int t = *osc_type;
    const float* p = PAR[t - 1];
    float xv = active ? x[i] : 1.0e9f;         // 1e9 -> not slow
    bool slow = active && is_slow(xv, p);
    if (active && !slow) {
        float mu = p[10], e = p[11];
        float sgn  = (xv > 0.0f) ? 1.0f : ((xv < 0.0f) ? -1.0f : 0.0f);
        float sim0 = fmaf(e, sgn, xv);
        out[i] = xla_tanhf(mu * sim0);         // omega (bitwise as ever)
    }
    unsigned long long mask = __ballot(slow);
    int lane = threadIdx.x & 63, wid = threadIdx.x >> 6;
    if (lane == 0) woff[wid] = (unsigned)__popcll(mask);
    __syncthreads();
    if (slow) {
        unsigned base = bbase[blockIdx.x];
        for (int w = 0; w < wid; ++w) base += woff[w];
        base += (unsigned)__popcll(mask & ((1ull << lane) - 1ull));
        wl[base] = (unsigned)i;
    }
}

// 4) dense worklist processing — all lanes useful
__global__ __launch_bounds__(256)
void k_process(const float* __restrict__ x, const int* __restrict__ osc_type,
               float* __restrict__ out, const unsigned* __restrict__ bbase,
               const unsigned* __restrict__ wl, int NB)
{
#pragma clang fp contract(off)
    unsigned tid = blockIdx.x * 256u + threadIdx.x;
    unsigned total = bbase[NB];
    if (tid >= total) return;
    int i = (int)wl[tid];
    int t = *osc_type;
    const float* p = PAR[t - 1];
    float sim0, damp, omega;
    preamble(x[i], p, sim0, damp, omega);
    out[i] = (t == 1) ? loop_t1(sim0, damp, omega)
                      : loop_gen(p, sim0, damp, omega);
}

// Fallback: proven round-6 monolithic kernel (if ws too small).
__global__ __launch_bounds__(256)
void k_monolithic(const float* __restrict__ x, const int* __restrict__ osc_type,
                  float* __restrict__ out, int n)
{
#pragma clang fp contract(off)
    int i = blockIdx.x * 256 + threadIdx.x;
    if (i >= n) return;
    int t = *osc_type;
    const float* p = PAR[t - 1];
    float sim0, damp, omega;
    preamble(x[i], p, sim0, damp, omega);
    if (damp == 0.0f) { out[i] = omega; return; }
    out[i] = (t == 1) ? loop_t1(sim0, damp, omega)
                      : loop_gen(p, sim0, damp, omega);
}

extern "C" void kernel_launch(void* const* d_in, const int* in_sizes, int n_in,
                              void* d_out, int out_size, void* d_ws, size_t ws_size,
                              hipStream_t stream) {
    const float* x        = (const float*)d_in[0];
    const int*   osc_type = (const int*)d_in[1];
    float*       out      = (float*)d_out;
    int n = in_sizes[0];
    int NB = (n + 255) / 256;

    size_t needed = ((size_t)NB + (size_t)NB + 1 + (size_t)n) * sizeof(unsigned);
    if (ws_size >= needed) {
        unsigned* bcount = (unsigned*)d_ws;
        unsigned* bbase  = bcount + NB;        // NB+1 entries
        unsigned* wl     = bbase + NB + 1;     // n entries
        k_count  <<<NB, 256, 0, stream>>>(x, osc_type, bcount, n);
        k_scan   <<<1, 256, 0, stream>>>(bcount, bbase, NB);
        k_fill   <<<NB, 256, 0, stream>>>(x, osc_type, out, bbase, wl, n);
        k_process<<<NB, 256, 0, stream>>>(x, osc_type, out, bbase, wl, NB);
    } else {
        k_monolithic<<<NB, 256, 0, stream>>>(x, osc_type, out, n);
    }
}

// Round 9
// 50.100 us; speedup vs baseline: 4.9643x; 1.4031x over previous
//
#include <hip/hip_runtime.h>
#include <math.h>

// Lee Oscillator: per-element 100-step chaotic recurrence, time-max-pooled.
// Bitwise-matches jax/XLA-CPU f32 semantics (PROVEN: rounds 6/7/8 absmax=0.0).
// The arithmetic (xla_tanhf/xla_expf/fusion pattern) must not change.
//
// Round-9: extended PROVABLY-bitwise fast path. |D|=|E1-I1| < 2 a priori, so
// if 2*damp < |omega|*2^-26 then every L_t = fma(D_t,damp,omega) rounds to
// omega (gap(omega) >= |omega|*2^-25 for normal omega; denormal gap 2^-149 is
// even larger than the bound; omega==0 -> damp==1 -> routed slow). Slow set
// shrinks 32.5% -> ~15.5% (|sim0| <~ 0.196). Routing is correctness-neutral:
// a borderline element run through the loop returns omega anyway.

#define N_STEPS 100

typedef float v2f __attribute__((ext_vector_type(2)));
__device__ __forceinline__ v2f splat2(float s){ v2f v; v.x = s; v.y = s; return v; }

// (a1,a2,a3,a4,b1,b2,b3,b4,xi_E,xi_I,mu,e,k) for oscillator types 1..8 (f32)
__constant__ float PAR[8][13] = {
    { 0.0f,  5.0f,  5.0f,  1.0f,  0.0f, -1.0f,  1.0f,  0.0f, 0.0f, 0.0f, 5.0f, 0.001f, 500.0f},
    { 0.5f,  0.55f, 0.55f, -0.5f,  0.5f, -0.55f, -0.55f, -0.5f, 0.0f, 0.0f, 1.0f, 0.001f, 50.0f},
    { 0.5f,  0.6f,  0.55f,  0.5f, -0.5f, -0.6f,  -0.55f,  0.5f, 0.0f, 0.0f, 1.0f, 0.001f, 50.0f},
    {-0.5f,  0.55f, 0.55f, -0.5f, -0.5f, -0.55f, -0.55f,  0.5f, 0.0f, 0.0f, 1.0f, 0.001f, 50.0f},
    {-0.9f,  0.9f,  0.9f,  -0.9f,  0.9f, -0.9f,  -0.9f,   0.9f, 0.0f, 0.0f, 1.0f, 0.001f, 50.0f},
    {-0.9f,  0.9f,  0.9f,  -0.9f,  0.9f, -0.9f,  -0.9f,   0.9f, 0.0f, 0.0f, 1.0f, 0.001f, 300.0f},
    {-5.0f,  5.0f,  5.0f,  -5.0f,  1.0f, -1.0f,  -1.0f,   1.0f, 0.0f, 0.0f, 1.0f, 0.001f, 50.0f},
    {-5.0f,  5.0f,  5.0f,  -5.0f,  1.0f, -1.0f,  -1.0f,   1.0f, 0.0f, 0.0f, 1.0f, 0.001f, 300.0f},
};

// XLA CPU f32 tanh — scalar form. [bitwise-verified rounds 6/7/8]
__device__ __forceinline__ float xla_tanhf(float x) {
#pragma clang fp contract(off)
    float ax = fabsf(x);
    float xc = fminf(fmaxf(x, -7.99881172180175781f), 7.99881172180175781f);
    float x2 = xc * xc;
    float p = -2.76076847742355e-16f;
    p = fmaf(p, x2, 2.00018790482477e-13f);
    p = fmaf(p, x2, -8.60467152213735e-11f);
    p = fmaf(p, x2, 5.12229709037114e-08f);
    p = fmaf(p, x2, 1.48572235717979e-05f);
    p = fmaf(p, x2, 6.37261928875436e-04f);
    p = fmaf(p, x2, 4.89352455891786e-03f);
    float num = xc * p;
    float q = 1.19825839466702e-06f;
    q = fmaf(q, x2, 1.18534705686654e-04f);
    q = fmaf(q, x2, 2.26843463243900e-03f);
    q = fmaf(q, x2, 4.89352518554385e-03f);
    float r = num / q;                       // IEEE f32 divide
    return (ax < 0.0004f) ? x : r;
}

// Packed 2-wide tanh: SAME per-component IEEE ops, packed for v_pk_fma_f32.
__device__ __forceinline__ v2f xla_tanh2(v2f x) {
#pragma clang fp contract(off)
    const float C = 7.99881172180175781f;
    v2f xc = __builtin_elementwise_min(__builtin_elementwise_max(x, splat2(-C)), splat2(C));
    v2f x2 = xc * xc;
    v2f p = splat2(-2.76076847742355e-16f);
    p = __builtin_elementwise_fma(p, x2, splat2(2.00018790482477e-13f));
    p = __builtin_elementwise_fma(p, x2, splat2(-8.60467152213735e-11f));
    p = __builtin_elementwise_fma(p, x2, splat2(5.12229709037114e-08f));
    p = __builtin_elementwise_fma(p, x2, splat2(1.48572235717979e-05f));
    p = __builtin_elementwise_fma(p, x2, splat2(6.37261928875436e-04f));
    p = __builtin_elementwise_fma(p, x2, splat2(4.89352455891786e-03f));
    v2f num = xc * p;
    v2f q = splat2(1.19825839466702e-06f);
    q = __builtin_elementwise_fma(q, x2, splat2(1.18534705686654e-04f));
    q = __builtin_elementwise_fma(q, x2, splat2(2.26843463243900e-03f));
    q = __builtin_elementwise_fma(q, x2, splat2(4.89352518554385e-03f));
    float rE = num.x / q.x;                  // IEEE f32 divides
    float rI = num.y / q.y;
    v2f r;
    r.x = (fabsf(x.x) < 0.0004f) ? x.x : rE;
    r.y = (fabsf(x.y) < 0.0004f) ? x.y : rI;
    return r;
}

// XLA CPU f32 exp (Cephes/Eigen pexp), FMA-contracted. [bitwise-verified]
__device__ __forceinline__ float xla_expf(float x) {
#pragma clang fp contract(off)
    float xc = fminf(fmaxf(x, -88.3762626647949f), 88.3762626647950f);
    float fx = floorf(fmaf(xc, 1.44269504088896341f, 0.5f));
    float r = fmaf(fx, -0.693359375f, xc);
    r = fmaf(fx, 2.12194440e-4f, r);
    float r2 = r * r;
    float y = 1.9875691500e-4f;
    y = fmaf(y, r, 1.3981999507e-3f);
    y = fmaf(y, r, 8.3334519073e-3f);
    y = fmaf(y, r, 4.1665795894e-2f);
    y = fmaf(y, r, 1.6666665459e-1f);
    y = fmaf(y, r, 5.0000001201e-1f);
    y = fmaf(y, r2, r);
    y = y + 1.0f;
    int n2 = (int)fx;
    float p2n = __int_as_float((n2 + 127) << 23);   // n==-127 -> +0.0
    return y * p2n;
}

// Shared per-element preamble (bitwise-identical everywhere).
__device__ __forceinline__ void preamble(float xv, const float* p,
                                         float& sim0, float& damp, float& omega) {
#pragma clang fp contract(off)
    float mu = p[10], e = p[11], k = p[12];
    float sgn  = (xv > 0.0f) ? 1.0f : ((xv < 0.0f) ? -1.0f : 0.0f);
    sim0 = fmaf(e, sgn, xv);                  // fadd(x, fmul(e,sgn)) fused
    float targ = (-k * sim0) * sim0;          // two plain muls
    damp  = xla_expf(targ);
    omega = xla_tanhf(mu * sim0);
}

// Routing predicate (PROVABLY bitwise-neutral, see header). fast <=>
// 2*damp < |omega|*2^-26  =>  |D*damp| < gap(omega)/2 for |D|<2  =>
// fma(D,damp,omega) == omega at every step  =>  out == omega.
__device__ __forceinline__ bool fast_omega(float damp, float omega) {
    return (2.0f * damp) < (fabsf(omega) * 0x1p-26f);
}

// 100-step loop, type-1 specialization (a1=b1=0, a4=1, xi=0), pk-packed.
// Per-component ops bitwise-identical to the round-6 verified scalar loop.
__device__ __forceinline__ float loop_t1(float sim0, float damp, float omega) {
#pragma clang fp contract(off)
    float E = 0.2f, I = 0.0f;
    float Dmax = -INFINITY;
    for (int s = 0; s < N_STEPS; ++s) {
        float tE = 5.0f * E;                   // round(a2*E)  (0*L unfolded)
        v2f mulc; mulc.x = -5.0f; mulc.y = -1.0f;
        v2f iv   = splat2(I);
        v2f addv; addv.x = tE;    addv.y = E;
        v2f u = __builtin_elementwise_fma(mulc, iv, addv);  // (uE, E-I)
        float sE = u.x + sim0;                 // plain fadd (a4==1 folded)
        v2f pre; pre.x = sE; pre.y = u.y;
        v2f args = splat2(5.0f) * pre;         // (argE, argI)
        v2f t = xla_tanh2(args);
        float D = t.x - t.y;                   // plain fsub
        Dmax = fmaxf(Dmax, D);
        E = t.x; I = t.y;
    }
    return fmaf(Dmax, damp, omega);            // == max_t fma(D_t,damp,omega)
}

// Generic-type loop (L feedback), proven scalar form.
__device__ __forceinline__ float loop_gen(const float* p, float sim0,
                                          float damp, float omega) {
#pragma clang fp contract(off)
    float a1 = p[0], a2 = p[1], a3 = p[2], a4 = p[3];
    float b1 = p[4], b2 = p[5], b3 = p[6], b4 = p[7];
    float xiE = p[8], xiI = p[9], mu = p[10];
    float nb2 = -b2;
    float E = 0.2f, I = 0.0f, L = 0.2f;
    float m = -INFINITY;
    for (int s = 0; s < N_STEPS; ++s) {
        float tE = a2 * E;
        float uE = fmaf(a1, L, tE);
        uE = fmaf(-a3, I, uE);
        uE = fmaf(a4, sim0, uE);
        uE = uE - xiE;
        float argE = mu * uE;
        float tI = nb2 * E;
        float uI = fmaf(b1, L, tI);
        uI = fmaf(-b3, I, uI);
        uI = fmaf(b4, sim0, uI);
        uI = uI - xiI;
        float argI = mu * uI;
        float E1 = xla_tanhf(argE);
        float I1 = xla_tanhf(argI);
        float d = E1 - I1;
        L = fmaf(d, damp, omega);
        E = E1; I = I1;
        m = fmaxf(m, L);
    }
    return m;
}

// ---------------- kernels ----------------

// 1) per-block slow-lane count (ballot + popc, no atomics)
__global__ __launch_bounds__(256)
void k_count(const float* __restrict__ x, const int* __restrict__ osc_type,
             unsigned* __restrict__ bcount, int n)
{
    __shared__ unsigned wc[4];
    int i = blockIdx.x * 256 + threadIdx.x;
    int t = *osc_type;
    const float* p = PAR[t - 1];
    bool slow = false;
    if (i < n) {
        float sim0, damp, omega;
        preamble(x[i], p, sim0, damp, omega);
        slow = !fast_omega(damp, omega);
    }
    unsigned long long mask = __ballot(slow);
    int lane = threadIdx.x & 63, wid = threadIdx.x >> 6;
    if (lane == 0) wc[wid] = (unsigned)__popcll(mask);
    __syncthreads();
    if (threadIdx.x == 0) bcount[blockIdx.x] = wc[0] + wc[1] + wc[2] + wc[3];
}

// 2) exclusive scan of NB block counts -> bbase[0..NB-1], bbase[NB] = total
__global__ __launch_bounds__(256)
void k_scan(const unsigned* __restrict__ bcount, unsigned* __restrict__ bbase,
            int NB)
{
    __shared__ unsigned sums[256];
    int tid = threadIdx.x;
    int items = (NB + 255) / 256;
    unsigned s = 0;
    for (int j = 0; j < items; ++j) {
        int idx = tid * items + j;
        s += (idx < NB) ? bcount[idx] : 0u;
    }
    sums[tid] = s;
    __syncthreads();
    for (int off = 1; off < 256; off <<= 1) {
        unsigned v = (tid >= off) ? sums[tid - off] : 0u;
        __syncthreads();
        sums[tid] += v;
        __syncthreads();
    }
    unsigned run = sums[tid] - s;              // exclusive base for this thread
    for (int j = 0; j < items; ++j) {
        int idx = tid * items + j;
        if (idx < NB) { bbase[idx] = run; run += bcount[idx]; }
    }
    if (tid == 255) bbase[NB] = sums[255];     // grand total
}

// 3) fast lanes -> out = omega; slow lanes -> wl[bbase[bid] + local prefix]
__global__ __launch_bounds__(256)
void k_fill(const float* __restrict__ x, const int* __restrict__ osc_type,
            float* __restrict__ out, const unsigned* __restrict__ bbase,
            unsigned* __restrict__ wl, int n)
{
#pragma clang fp contract(off)
    __shared__ unsigned woff[4];
    int i = blockIdx.x * 256 + threadIdx.x;
    bool active = (i < n);
    int t = *osc_type;
    const float* p = PAR[t - 1];
    float xv = active ? x[i] : 1.0e9f;         // 1e9 -> fast (and inactive)
    float sim0, damp, omega;
    preamble(xv, p, sim0, damp, omega);
    bool slow = active && !fast_omega(damp, omega);
    if (active && !slow) out[i] = omega;       // proven == loop output
    unsigned long long mask = __ballot(slow);
    int lane = threadIdx.x & 63, wid = threadIdx.x >> 6;
    if (lane == 0) woff[wid] = (unsigned)__popcll(mask);
    __syncthreads();
    if (slow) {
        unsigned base = bbase[blockIdx.x];
        for (int w = 0; w < wid; ++w) base += woff[w];
        base += (unsigned)__popcll(mask & ((1ull << lane) - 1ull));
        wl[base] = (unsigned)i;
    }
}

// 4) dense worklist processing — 128-thread blocks for CU-level balance,
//    bounded grid + stride loop.
__global__ __launch_bounds__(128)
void k_process(const float* __restrict__ x, const int* __restrict__ osc_type,
               float* __restrict__ out, const unsigned* __restrict__ bbase,
               const unsigned* __restrict__ wl, int NB)
{
#pragma clang fp contract(off)
    unsigned total = bbase[NB];
    int t = *osc_type;
    const float* p = PAR[t - 1];
    unsigned stride = gridDim.x * 128u;
    for (unsigned tid = blockIdx.x * 128u + threadIdx.x; tid < total; tid += stride) {
        int i = (int)wl[tid];
        float sim0, damp, omega;
        preamble(x[i], p, sim0, damp, omega);
        out[i] = (t == 1) ? loop_t1(sim0, damp, omega)
                          : loop_gen(p, sim0, damp, omega);
    }
}

// Fallback: proven monolithic kernel (if ws too small), with extended shortcut.
__global__ __launch_bounds__(256)
void k_monolithic(const float* __restrict__ x, const int* __restrict__ osc_type,
                  float* __restrict__ out, int n)
{
#pragma clang fp contract(off)
    int i = blockIdx.x * 256 + threadIdx.x;
    if (i >= n) return;
    int t = *osc_type;
    const float* p = PAR[t - 1];
    float sim0, damp, omega;
    preamble(x[i], p, sim0, damp, omega);
    if (fast_omega(damp, omega)) { out[i] = omega; return; }
    out[i] = (t == 1) ? loop_t1(sim0, damp, omega)
                      : loop_gen(p, sim0, damp, omega);
}

extern "C" void kernel_launch(void* const* d_in, const int* in_sizes, int n_in,
                              void* d_out, int out_size, void* d_ws, size_t ws_size,
                              hipStream_t stream) {
    const float* x        = (const float*)d_in[0];
    const int*   osc_type = (const int*)d_in[1];
    float*       out      = (float*)d_out;
    int n = in_sizes[0];
    int NB = (n + 255) / 256;

    size_t needed = ((size_t)NB + (size_t)NB + 1 + (size_t)n) * sizeof(unsigned);
    if (ws_size >= needed) {
        unsigned* bcount = (unsigned*)d_ws;
        unsigned* bbase  = bcount + NB;        // NB+1 entries
        unsigned* wl     = bbase + NB + 1;     // n entries
        k_count  <<<NB, 256, 0, stream>>>(x, osc_type, bcount, n);
        k_scan   <<<1, 256, 0, stream>>>(bcount, bbase, NB);
        k_fill   <<<NB, 256, 0, stream>>>(x, osc_type, out, bbase, wl, n);
        int pblocks = 2048;                    // grid-stride covers any total
        k_process<<<pblocks, 128, 0, stream>>>(x, osc_type, out, bbase, wl, NB);
    } else {
        k_monolithic<<<NB, 256, 0, stream>>>(x, osc_type, out, n);
    }
}